// Round 18
// baseline (82.222 us; speedup 1.0000x reference)
//
#include <hip/hip_runtime.h>
#include <hip/hip_bf16.h>
#include <stdint.h>

#define DIM 1024
#define NTOK 8192

#define BM 128
#define BN 128
#define BK 64            // fp8: 64 bytes per row-tile

typedef unsigned char uchar;
typedef __attribute__((ext_vector_type(4)))  int   i32x4;
typedef __attribute__((ext_vector_type(8)))  int   i32x8;
typedef __attribute__((ext_vector_type(16))) float f32x16;

// async global->LDS, 16B per lane (dest = wave base + lane*16, linear)
#define GLOAD_LDS16(g, l)                                                \
    __builtin_amdgcn_global_load_lds(                                    \
        (const __attribute__((address_space(1))) void*)(g),              \
        (__attribute__((address_space(3))) void*)(l), 16, 0, 0)

__device__ __forceinline__ unsigned short f2bf(float f) {
    union { float f; uint32_t u; } v; v.f = f;
    uint32_t u = v.u;
    u += 0x7FFFu + ((u >> 16) & 1u);   // RNE
    return (unsigned short)(u >> 16);
}
__device__ __forceinline__ float bf2f(unsigned short h) {
    union { uint32_t u; float f; } v; v.u = ((uint32_t)h) << 16; return v.f;
}

// Closed-form uniform cubic B-spline (knots -2.2 + 0.55*i; weights s0..s4)
__device__ __forceinline__ float spline_eval(float xn, float s0, float s1,
                                             float s2, float s3, float s4) {
    const float xc = fminf(fmaxf(xn, -1.0f), 1.0f);
    const float u = (xc + 2.2f) * (1.0f / 0.55f);
    int j = (int)u;
    j = j < 2 ? 2 : (j > 5 ? 5 : j);
    const float t = u - (float)j;
    const float omt = 1.0f - t;
    const float t2 = t * t, t3 = t2 * t;
    const float w0 = omt * omt * omt * (1.0f / 6.0f);
    const float w1 = (3.0f * t3 - 6.0f * t2 + 4.0f) * (1.0f / 6.0f);
    const float w2 = (-3.0f * t3 + 3.0f * t2 + 3.0f * t + 1.0f) * (1.0f / 6.0f);
    const float w3 = t3 * (1.0f / 6.0f);
    float so;
    if (j == 2)      so = w1 * s0 + w2 * s1 + w3 * s2;
    else if (j == 3) so = w0 * s0 + w1 * s1 + w2 * s2 + w3 * s3;
    else if (j == 4) so = w0 * s1 + w1 * s2 + w2 * s3 + w3 * s4;
    else             so = w0 * s2 + w1 * s3 + w2 * s4;
    return so;
}

__device__ __forceinline__ int pack_fp8x4(float a, float b, float c, float d) {
    int p = __builtin_amdgcn_cvt_pk_fp8_f32(a, b, 0, false);   // bytes 0,1
    p = __builtin_amdgcn_cvt_pk_fp8_f32(c, d, p, true);        // bytes 2,3
    return p;
}

// ---------------------------------------------------------------------------
// Kernel 0 (wave-per-row, no LDS/no barriers):
//   blocks [0, NTOK/4): 4 waves x 1 row RMSNorm -> xn8 (fp8) + rr[row]
//   blocks [NTOK/4, NTOK/4 + DIM/4): 4 waves x 1 W row f32 -> fp8
// ---------------------------------------------------------------------------
__global__ __launch_bounds__(256) void prep_kernel(
    const float* __restrict__ x, const float* __restrict__ nw,
    const float* __restrict__ W,
    uchar* __restrict__ xn8, uchar* __restrict__ W8,
    float* __restrict__ rr)
{
    const int bid = blockIdx.x;
    const int t = threadIdx.x;
    const int lane = t & 63, w = t >> 6;

    if (bid >= NTOK / 4) {                 // W conversion: 4 rows per block
        const int row = (bid - NTOK / 4) * 4 + w;
        const float4* src = reinterpret_cast<const float4*>(W + (size_t)row * DIM) + lane * 4;
        const float4 a = src[0], b = src[1], c = src[2], d = src[3];
        int4 o;
        o.x = pack_fp8x4(a.x, a.y, a.z, a.w);
        o.y = pack_fp8x4(b.x, b.y, b.z, b.w);
        o.z = pack_fp8x4(c.x, c.y, c.z, c.w);
        o.w = pack_fp8x4(d.x, d.y, d.z, d.w);
        reinterpret_cast<int4*>(W8 + (size_t)row * DIM)[lane] = o;
        return;
    }

    const int row = bid * 4 + w;
    const float4* xr = reinterpret_cast<const float4*>(x + (size_t)row * DIM) + lane * 4;
    const float4 a = xr[0], b = xr[1], c = xr[2], d = xr[3];

    float ssq = a.x*a.x + a.y*a.y + a.z*a.z + a.w*a.w
              + b.x*b.x + b.y*b.y + b.z*b.z + b.w*b.w
              + c.x*c.x + c.y*c.y + c.z*c.z + c.w*c.w
              + d.x*d.x + d.y*d.y + d.z*d.z + d.w*d.w;
    #pragma unroll
    for (int off = 32; off; off >>= 1) ssq += __shfl_xor(ssq, off, 64);

    const float r = rsqrtf(ssq * (1.0f / DIM) + 1e-6f);
    if (lane == 0) rr[row] = r;

    const float4* nwr = reinterpret_cast<const float4*>(nw) + lane * 4;
    const float4 na = nwr[0], nb = nwr[1], nc = nwr[2], nd = nwr[3];
    int4 o;
    o.x = pack_fp8x4(a.x*r*na.x, a.y*r*na.y, a.z*r*na.z, a.w*r*na.w);
    o.y = pack_fp8x4(b.x*r*nb.x, b.y*r*nb.y, b.z*r*nb.z, b.w*r*nb.w);
    o.z = pack_fp8x4(c.x*r*nc.x, c.y*r*nc.y, c.z*r*nc.z, c.w*r*nc.w);
    o.w = pack_fp8x4(d.x*r*nd.x, d.y*r*nd.y, d.z*r*nd.z, d.w*r*nd.w);
    reinterpret_cast<int4*>(xn8 + (size_t)row * DIM)[lane] = o;
}

// ---------------------------------------------------------------------------
// Kernel 1: MX-fp8 MFMA GEMM C[n,d] = sum_k xn[n,k] * W[d,k], fused epilogue:
//   out[n,d] = x[n,d] + (C[n,d] + spline(x*r*nw, sw[d,:])) * gamma[d]
// r14 (best, 38.0us) with __launch_bounds__(1024, 8): hard VGPR<=64 cap so
// TWO 16-wave blocks co-reside per CU = 32 waves/CU (r14's VGPR=88 silently
// capped residency at ONE block = 16 waves/CU). Epilogue restructured for low
// register pressure: sw/nw/gamma loaded per row-iteration (non-restrict ->
// not hoistable across out stores). Everything else identical to r14.
// ---------------------------------------------------------------------------
__global__ __launch_bounds__(1024, 8) void gemm_ep_kernel(
    const uchar* __restrict__ A,   // xn fp8 [NTOK][DIM]
    const uchar* __restrict__ B,   // W  fp8 [DIM][DIM]
    const float* __restrict__ x,
    const float* __restrict__ rrow,         // [NTOK]
    const float* nw,                        // [DIM]   (no restrict: see epilogue)
    const float* sw,                        // [DIM][5]
    const float* gamma,                     // [DIM]
    float* __restrict__ out)
{
    __shared__ uchar SB[4 * 16384];              // 64 KB: ring-4, A 8KB + B 8KB

    const int tid = threadIdx.x;
    const int lane = tid & 63, wid = tid >> 6;   // wid 0..15

    // XCD swizzle: 512 blocks, xcd = bid&7 gets 8 bm panels x all 8 bn
    const int bid = blockIdx.x;
    const int swz = (bid & 7) * 64 + (bid >> 3);
    const int bm = swz >> 3, bn = swz & 7;

    const int wm = wid >> 2, wn = wid & 3;       // 4x4 grid of 32x32 tiles

    f32x16 acc = {};

    // ---- staging: waves 0-7 stage A rows, waves 8-15 stage B rows.
    //      s = tid&511: row s>>2 (0..127), 16B unit s&3 (linear dest);
    //      global source unit pre-swizzled by ((s>>3)&3) = (row>>1)&3
    const int s = tid & 511;
    const int srow = s >> 2;
    const int scol = ((s & 3) ^ ((s >> 3) & 3)) * 16;     // bytes
    const uchar* Gsrc = (tid < 512)
        ? A + (size_t)(bm * BM + srow) * DIM + scol
        : B + (size_t)(bn * BN + srow) * DIM + scol;
    const int oS = (tid < 512 ? 0 : 8192) + s * 16;

    // ---- fragment read offsets (swizzled, verified r9..r17) ----
    const int xorv = (lane >> 1) & 3;
    const int u0 = ((lane >> 5) * 2) ^ xorv;  // 16B unit of k-bytes [kg*32,+16)
    const int u1 = u0 ^ 1;
    const int aBase = (wm * 32 + (lane & 31)) * 64;
    const int bBase = 8192 + (wn * 32 + (lane & 31)) * 64;

#define STAGE(bi, kt) do {                                           \
        GLOAD_LDS16(Gsrc + (size_t)(kt) * BK, SB + (bi) * 16384 + oS); \
    } while (0)

#define LD8(dst, base) do {                                          \
        const i32x4 lo_ = *reinterpret_cast<const i32x4*>(sb_ + (base) + u0 * 16); \
        const i32x4 hi_ = *reinterpret_cast<const i32x4*>(sb_ + (base) + u1 * 16); \
        dst = (i32x8){lo_[0], lo_[1], lo_[2], lo_[3],                \
                      hi_[0], hi_[1], hi_[2], hi_[3]};               \
    } while (0)

#define COMP(bi) do {                                                \
        const uchar* sb_ = SB + (bi) * 16384;                        \
        i32x8 a0, b0;                                                \
        LD8(a0, aBase);                                              \
        LD8(b0, bBase);                                              \
        acc = __builtin_amdgcn_mfma_scale_f32_32x32x64_f8f6f4(       \
            a0, b0, acc, 0, 0, 0, 0x7F7F7F7F, 0, 0x7F7F7F7F);        \
    } while (0)

#define W2v asm volatile("s_waitcnt vmcnt(2)" ::: "memory")
#define W1v asm volatile("s_waitcnt vmcnt(1)" ::: "memory")
#define W0v asm volatile("s_waitcnt vmcnt(0)" ::: "memory")
#define BAR __builtin_amdgcn_s_barrier()

    STAGE(0, 0);
    STAGE(1, 1);
    #pragma unroll 1
    for (int k4 = 0; k4 < 12; k4 += 4) {
        STAGE(2, k4 + 2); W2v; BAR; COMP(0);
        STAGE(3, k4 + 3); W2v; BAR; COMP(1);
        STAGE(0, k4 + 4); W2v; BAR; COMP(2);
        STAGE(1, k4 + 5); W2v; BAR; COMP(3);
    }
    STAGE(2, 14); W2v; BAR; COMP(0);   // kt=12
    STAGE(3, 15); W2v; BAR; COMP(1);   // kt=13
    W1v; BAR; COMP(2);                 // kt=14
    W0v; BAR; COMP(3);                 // kt=15
    __syncthreads();                   // all SB reads done before Cb overwrite

#undef STAGE
#undef LD8
#undef COMP
#undef W2v
#undef W1v
#undef W0v
#undef BAR

    // ---- fused epilogue: single-pass bf16 C-tile [128][136] (34 KB) ----
    unsigned short* Cb = reinterpret_cast<unsigned short*>(SB);
    {
        // C/D 32x32 layout: col=lane&31, row=(r&3)+8*(r>>2)+4*(lane>>5)
        const int crow0 = wm * 32 + 4 * (lane >> 5);
        const int ccol0 = wn * 32 + (lane & 31);
        #pragma unroll
        for (int r = 0; r < 16; ++r) {
            const int lr = crow0 + (r & 3) + 8 * (r >> 2);
            Cb[lr * 136 + ccol0] = f2bf(acc[r]);
        }
    }
    __syncthreads();

    // Low-pressure epilogue: per-row loop reloads sw/gamma/nw (non-restrict
    // pointers -> compiler must not hoist across out stores; L1-hot).
    const int colg = bn * BN + (tid & 31) * 4;   // 4 consecutive output cols

    #pragma unroll 1
    for (int v = 0; v < 4; ++v) {
        const int lr = (tid >> 5) * 4 + v;           // 0..127
        const size_t grow = (size_t)(bm * BM + lr);
        const ushort4 cb4 = *reinterpret_cast<const ushort4*>(&Cb[lr * 136 + (tid & 31) * 4]);
        const float4 xv = *reinterpret_cast<const float4*>(x + grow * DIM + colg);
        const float rv = rrow[grow];
        const float4 gv  = *reinterpret_cast<const float4*>(gamma + colg);
        const float4 nwv = *reinterpret_cast<const float4*>(nw + colg);
        const float4 s0 = *reinterpret_cast<const float4*>(sw + (size_t)colg * 5);
        const float4 s1 = *reinterpret_cast<const float4*>(sw + (size_t)colg * 5 + 4);
        const float4 s2 = *reinterpret_cast<const float4*>(sw + (size_t)colg * 5 + 8);
        const float4 s3 = *reinterpret_cast<const float4*>(sw + (size_t)colg * 5 + 12);
        const float4 s4 = *reinterpret_cast<const float4*>(sw + (size_t)colg * 5 + 16);
        float4 ov;
        ov.x = xv.x + (bf2f(cb4.x) + spline_eval(xv.x * rv * nwv.x, s0.x, s0.y, s0.z, s0.w, s1.x)) * gv.x;
        ov.y = xv.y + (bf2f(cb4.y) + spline_eval(xv.y * rv * nwv.y, s1.y, s1.z, s1.w, s2.x, s2.y)) * gv.y;
        ov.z = xv.z + (bf2f(cb4.z) + spline_eval(xv.z * rv * nwv.z, s2.z, s2.w, s3.x, s3.y, s3.z)) * gv.z;
        ov.w = xv.w + (bf2f(cb4.w) + spline_eval(xv.w * rv * nwv.w, s3.w, s4.x, s4.y, s4.z, s4.w)) * gv.w;
        *reinterpret_cast<float4*>(out + grow * DIM + colg) = ov;
    }
}

// ---------------------------------------------------------------------------
extern "C" void kernel_launch(void* const* d_in, const int* in_sizes, int n_in,
                              void* d_out, int out_size, void* d_ws, size_t ws_size,
                              hipStream_t stream) {
    const float* x     = (const float*)d_in[0];
    const float* nw    = (const float*)d_in[1];
    const float* W     = (const float*)d_in[2];
    const float* sw    = (const float*)d_in[3];
    const float* gamma = (const float*)d_in[4];
    float* out = (float*)d_out;

    uchar* xn8 = (uchar*)d_ws;                                // 8 MB fp8 x_norm
    uchar* W8  = xn8 + (size_t)NTOK * DIM;                    // 1 MB fp8 W
    float* rr  = (float*)(W8 + (size_t)DIM * DIM);            // 32 KB row rsqrt

    prep_kernel<<<dim3(NTOK / 4 + DIM / 4), 256, 0, stream>>>(x, nw, W, xn8, W8, rr);
    gemm_ep_kernel<<<dim3((NTOK / BM) * (DIM / BN)), dim3(1024), 0, stream>>>(
        xn8, W8, x, rr, nw, sw, gamma, out);
}

// Round 20
// 58.231 us; speedup vs baseline: 1.4120x; 1.4120x over previous
//
#include <hip/hip_runtime.h>
#include <hip/hip_bf16.h>
#include <stdint.h>

#define DIM 1024
#define NTOK 8192

#define BM 128
#define BN 128
#define BK 64            // fp8: 64 bytes per row-tile

typedef unsigned char uchar;
typedef __attribute__((ext_vector_type(4)))  int   i32x4;
typedef __attribute__((ext_vector_type(8)))  int   i32x8;
typedef __attribute__((ext_vector_type(16))) float f32x16;

// async global->LDS, 16B per lane (dest = wave base + lane*16, linear)
#define GLOAD_LDS16(g, l)                                                \
    __builtin_amdgcn_global_load_lds(                                    \
        (const __attribute__((address_space(1))) void*)(g),              \
        (__attribute__((address_space(3))) void*)(l), 16, 0, 0)

__device__ __forceinline__ unsigned short f2bf(float f) {
    union { float f; uint32_t u; } v; v.f = f;
    uint32_t u = v.u;
    u += 0x7FFFu + ((u >> 16) & 1u);   // RNE
    return (unsigned short)(u >> 16);
}
__device__ __forceinline__ float bf2f(unsigned short h) {
    union { uint32_t u; float f; } v; v.u = ((uint32_t)h) << 16; return v.f;
}

// Closed-form uniform cubic B-spline (knots -2.2 + 0.55*i; weights s0..s4)
__device__ __forceinline__ float spline_eval(float xn, float s0, float s1,
                                             float s2, float s3, float s4) {
    const float xc = fminf(fmaxf(xn, -1.0f), 1.0f);
    const float u = (xc + 2.2f) * (1.0f / 0.55f);
    int j = (int)u;
    j = j < 2 ? 2 : (j > 5 ? 5 : j);
    const float t = u - (float)j;
    const float omt = 1.0f - t;
    const float t2 = t * t, t3 = t2 * t;
    const float w0 = omt * omt * omt * (1.0f / 6.0f);
    const float w1 = (3.0f * t3 - 6.0f * t2 + 4.0f) * (1.0f / 6.0f);
    const float w2 = (-3.0f * t3 + 3.0f * t2 + 3.0f * t + 1.0f) * (1.0f / 6.0f);
    const float w3 = t3 * (1.0f / 6.0f);
    float so;
    if (j == 2)      so = w1 * s0 + w2 * s1 + w3 * s2;
    else if (j == 3) so = w0 * s0 + w1 * s1 + w2 * s2 + w3 * s3;
    else if (j == 4) so = w0 * s1 + w1 * s2 + w2 * s3 + w3 * s4;
    else             so = w0 * s2 + w1 * s3 + w2 * s4;
    return so;
}

__device__ __forceinline__ int pack_fp8x4(float a, float b, float c, float d) {
    int p = __builtin_amdgcn_cvt_pk_fp8_f32(a, b, 0, false);   // bytes 0,1
    p = __builtin_amdgcn_cvt_pk_fp8_f32(c, d, p, true);        // bytes 2,3
    return p;
}

// ---------------------------------------------------------------------------
// Kernel 0 (wave-per-row, no LDS/no barriers):
//   blocks [0, NTOK/4): 4 waves x 1 row RMSNorm -> xn8 (fp8) + rr[row]
//   blocks [NTOK/4, NTOK/4 + DIM/4): 4 waves x 1 W row f32 -> fp8
// ---------------------------------------------------------------------------
__global__ __launch_bounds__(256) void prep_kernel(
    const float* __restrict__ x, const float* __restrict__ nw,
    const float* __restrict__ W,
    uchar* __restrict__ xn8, uchar* __restrict__ W8,
    float* __restrict__ rr)
{
    const int bid = blockIdx.x;
    const int t = threadIdx.x;
    const int lane = t & 63, w = t >> 6;

    if (bid >= NTOK / 4) {                 // W conversion: 4 rows per block
        const int row = (bid - NTOK / 4) * 4 + w;
        const float4* src = reinterpret_cast<const float4*>(W + (size_t)row * DIM) + lane * 4;
        const float4 a = src[0], b = src[1], c = src[2], d = src[3];
        int4 o;
        o.x = pack_fp8x4(a.x, a.y, a.z, a.w);
        o.y = pack_fp8x4(b.x, b.y, b.z, b.w);
        o.z = pack_fp8x4(c.x, c.y, c.z, c.w);
        o.w = pack_fp8x4(d.x, d.y, d.z, d.w);
        reinterpret_cast<int4*>(W8 + (size_t)row * DIM)[lane] = o;
        return;
    }

    const int row = bid * 4 + w;
    const float4* xr = reinterpret_cast<const float4*>(x + (size_t)row * DIM) + lane * 4;
    const float4 a = xr[0], b = xr[1], c = xr[2], d = xr[3];

    float ssq = a.x*a.x + a.y*a.y + a.z*a.z + a.w*a.w
              + b.x*b.x + b.y*b.y + b.z*b.z + b.w*b.w
              + c.x*c.x + c.y*c.y + c.z*c.z + c.w*c.w
              + d.x*d.x + d.y*d.y + d.z*d.z + d.w*d.w;
    #pragma unroll
    for (int off = 32; off; off >>= 1) ssq += __shfl_xor(ssq, off, 64);

    const float r = rsqrtf(ssq * (1.0f / DIM) + 1e-6f);
    if (lane == 0) rr[row] = r;

    const float4* nwr = reinterpret_cast<const float4*>(nw) + lane * 4;
    const float4 na = nwr[0], nb = nwr[1], nc = nwr[2], nd = nwr[3];
    int4 o;
    o.x = pack_fp8x4(a.x*r*na.x, a.y*r*na.y, a.z*r*na.z, a.w*r*na.w);
    o.y = pack_fp8x4(b.x*r*nb.x, b.y*r*nb.y, b.z*r*nb.z, b.w*r*nb.w);
    o.z = pack_fp8x4(c.x*r*nc.x, c.y*r*nc.y, c.z*r*nc.z, c.w*r*nc.w);
    o.w = pack_fp8x4(d.x*r*nd.x, d.y*r*nd.y, d.z*r*nd.z, d.w*r*nd.w);
    reinterpret_cast<int4*>(xn8 + (size_t)row * DIM)[lane] = o;
}

// ---------------------------------------------------------------------------
// Kernel 1: MX-fp8 MFMA GEMM C[n,d] = sum_k xn[n,k] * W[d,k], fused epilogue:
//   out[n,d] = x[n,d] + (C[n,d] + spline(x*r*nw, sw[d,:])) * gamma[d]
// 24-waves/CU attempt, vmcnt FIXED from r19: STAGE = 2 loads/thread, so the
// counted wait is W2 (= 2 loads of stage j+1 in flight, stage j retired),
// NOT r8's W4 (r8's STAGE was 4 loads). W0 only at the last phase.
// 512 threads (8 waves), ring-3 staging (48 KB -> 3 blocks/CU by LDS),
// __launch_bounds__(512,6) (VGPR<=85). Per-wave 32x64 = 2x
// mfma_scale_32x32x64_f8f6f4 (scales=1.0). Phase j: W2; BAR; COMP(j%3);
// STAGE((j+2)%3, j+2) -- previous reader of that buffer is COMP(j-1),
// separated by this phase's BAR. Verified swizzle pair; low-pressure
// epilogue (per-row reloads via non-restrict pointers).
// ---------------------------------------------------------------------------
__global__ __launch_bounds__(512, 6) void gemm_ep_kernel(
    const uchar* __restrict__ A,   // xn fp8 [NTOK][DIM]
    const uchar* __restrict__ B,   // W  fp8 [DIM][DIM]
    const float* __restrict__ x,
    const float* __restrict__ rrow,         // [NTOK]
    const float* nw,                        // [DIM]   (no restrict: epilogue)
    const float* sw,                        // [DIM][5]
    const float* gamma,                     // [DIM]
    float* __restrict__ out)
{
    __shared__ uchar SB[3 * 16384];              // 48 KB: ring-3, A 8KB + B 8KB

    const int tid = threadIdx.x;
    const int lane = tid & 63, wid = tid >> 6;   // wid 0..7

    // XCD swizzle: 512 blocks, xcd = bid&7 gets 8 bm panels x all 8 bn
    const int bid = blockIdx.x;
    const int swz = (bid & 7) * 64 + (bid >> 3);
    const int bm = swz >> 3, bn = swz & 7;

    const int wm = wid >> 1, wn = wid & 1;       // wm: 32-row slice, wn: 64-col slice

    f32x16 acc[2] = {};

    // ---- staging: thread t -> row t>>2 (0..127), 16B unit t&3 (linear dest);
    //      global source unit pre-swizzled by ((t>>3)&3) = (row>>1)&3
    const int srow = tid >> 2;
    const int scol = ((tid & 3) ^ ((tid >> 3) & 3)) * 16;     // bytes
    const uchar* Ag = A + (size_t)(bm * BM + srow) * DIM + scol;
    const uchar* Bg = B + (size_t)(bn * BN + srow) * DIM + scol;
    const int oA = tid * 16;                  // A rows 0..127 -> [0, 8192)
    const int oB = 8192 + tid * 16;           // B rows 0..127 -> [8192, 16384)

    // ---- fragment read offsets (swizzled, verified r9..r17) ----
    const int xorv = (lane >> 1) & 3;
    const int u0 = ((lane >> 5) * 2) ^ xorv;  // 16B unit of k-bytes [kg*32,+16)
    const int u1 = u0 ^ 1;
    const int aBase = (wm * 32 + (lane & 31)) * 64;
    const int bBase = 8192 + (wn * 64 + (lane & 31)) * 64;

#define STAGE(bi, kt) do {                                           \
        uchar* sb_ = SB + (bi) * 16384;                              \
        GLOAD_LDS16(Ag + (size_t)(kt) * BK, sb_ + oA);               \
        GLOAD_LDS16(Bg + (size_t)(kt) * BK, sb_ + oB);               \
    } while (0)

#define LD8(dst, base) do {                                          \
        const i32x4 lo_ = *reinterpret_cast<const i32x4*>(sb_ + (base) + u0 * 16); \
        const i32x4 hi_ = *reinterpret_cast<const i32x4*>(sb_ + (base) + u1 * 16); \
        dst = (i32x8){lo_[0], lo_[1], lo_[2], lo_[3],                \
                      hi_[0], hi_[1], hi_[2], hi_[3]};               \
    } while (0)

#define COMP(bi) do {                                                \
        const uchar* sb_ = SB + (bi) * 16384;                        \
        i32x8 a0, b0, b1;                                            \
        LD8(a0, aBase);                                              \
        LD8(b0, bBase);                                              \
        LD8(b1, bBase + 2048);                                       \
        acc[0] = __builtin_amdgcn_mfma_scale_f32_32x32x64_f8f6f4(    \
            a0, b0, acc[0], 0, 0, 0, 0x7F7F7F7F, 0, 0x7F7F7F7F);     \
        acc[1] = __builtin_amdgcn_mfma_scale_f32_32x32x64_f8f6f4(    \
            a0, b1, acc[1], 0, 0, 0, 0x7F7F7F7F, 0, 0x7F7F7F7F);     \
    } while (0)

#define W2v asm volatile("s_waitcnt vmcnt(2)" ::: "memory")
#define W0v asm volatile("s_waitcnt vmcnt(0)" ::: "memory")
#define BAR __builtin_amdgcn_s_barrier()

    STAGE(0, 0);
    STAGE(1, 1);
    // phase j: W2 (stage j retired, stage j+1 in flight); BAR; COMP(j%3);
    // STAGE((j+2)%3, j+2). 16 phases total; last two have nothing to stage.
    #pragma unroll 1
    for (int g = 0; g < 4; ++g) {
        const int kt = g * 3;
        W2v; BAR; COMP(0); STAGE(2, kt + 2);
        W2v; BAR; COMP(1); STAGE(0, kt + 3);
        W2v; BAR; COMP(2); STAGE(1, kt + 4);
    }
    W2v; BAR; COMP(0); STAGE(2, 14);   // kt=12
    W2v; BAR; COMP(1); STAGE(0, 15);   // kt=13
    W2v; BAR; COMP(2);                 // kt=14 (stages 14,15 outstanding -> W2 retires 14)
    W0v; BAR; COMP(0);                 // kt=15
    __syncthreads();                   // all SB reads done before Cb overwrite

#undef STAGE
#undef LD8
#undef COMP
#undef W2v
#undef W0v
#undef BAR

    // ---- fused epilogue: single-pass bf16 C-tile [128][136] (34 KB) ----
    unsigned short* Cb = reinterpret_cast<unsigned short*>(SB);
    {
        // C/D 32x32 layout: col=lane&31, row=(r&3)+8*(r>>2)+4*(lane>>5)
        const int crow0 = wm * 32 + 4 * (lane >> 5);
        const int ccol0 = wn * 64 + (lane & 31);
        #pragma unroll
        for (int j = 0; j < 2; ++j)
            #pragma unroll
            for (int r = 0; r < 16; ++r) {
                const int lr = crow0 + (r & 3) + 8 * (r >> 2);
                Cb[lr * 136 + ccol0 + j * 32] = f2bf(acc[j][r]);
            }
    }
    __syncthreads();

    // Low-pressure epilogue: per-row loop reloads sw/gamma/nw (non-restrict
    // -> not hoistable across out stores; all L1/L2-hot).
    const int colg = bn * BN + (tid & 31) * 4;   // 4 consecutive output cols

    #pragma unroll 1
    for (int v = 0; v < 8; ++v) {
        const int lr = (tid >> 5) * 8 + v;           // 0..127
        const size_t grow = (size_t)(bm * BM + lr);
        const ushort4 cb4 = *reinterpret_cast<const ushort4*>(&Cb[lr * 136 + (tid & 31) * 4]);
        const float4 xv = *reinterpret_cast<const float4*>(x + grow * DIM + colg);
        const float rv = rrow[grow];
        const float4 gv  = *reinterpret_cast<const float4*>(gamma + colg);
        const float4 nwv = *reinterpret_cast<const float4*>(nw + colg);
        const float4 s0 = *reinterpret_cast<const float4*>(sw + (size_t)colg * 5);
        const float4 s1 = *reinterpret_cast<const float4*>(sw + (size_t)colg * 5 + 4);
        const float4 s2 = *reinterpret_cast<const float4*>(sw + (size_t)colg * 5 + 8);
        const float4 s3 = *reinterpret_cast<const float4*>(sw + (size_t)colg * 5 + 12);
        const float4 s4 = *reinterpret_cast<const float4*>(sw + (size_t)colg * 5 + 16);
        float4 ov;
        ov.x = xv.x + (bf2f(cb4.x) + spline_eval(xv.x * rv * nwv.x, s0.x, s0.y, s0.z, s0.w, s1.x)) * gv.x;
        ov.y = xv.y + (bf2f(cb4.y) + spline_eval(xv.y * rv * nwv.y, s1.y, s1.z, s1.w, s2.x, s2.y)) * gv.y;
        ov.z = xv.z + (bf2f(cb4.z) + spline_eval(xv.z * rv * nwv.z, s2.z, s2.w, s3.x, s3.y, s3.z)) * gv.z;
        ov.w = xv.w + (bf2f(cb4.w) + spline_eval(xv.w * rv * nwv.w, s3.w, s4.x, s4.y, s4.z, s4.w)) * gv.w;
        *reinterpret_cast<float4*>(out + grow * DIM + colg) = ov;
    }
}

// ---------------------------------------------------------------------------
extern "C" void kernel_launch(void* const* d_in, const int* in_sizes, int n_in,
                              void* d_out, int out_size, void* d_ws, size_t ws_size,
                              hipStream_t stream) {
    const float* x     = (const float*)d_in[0];
    const float* nw    = (const float*)d_in[1];
    const float* W     = (const float*)d_in[2];
    const float* sw    = (const float*)d_in[3];
    const float* gamma = (const float*)d_in[4];
    float* out = (float*)d_out;

    uchar* xn8 = (uchar*)d_ws;                                // 8 MB fp8 x_norm
    uchar* W8  = xn8 + (size_t)NTOK * DIM;                    // 1 MB fp8 W
    float* rr  = (float*)(W8 + (size_t)DIM * DIM);            // 32 KB row rsqrt

    prep_kernel<<<dim3(NTOK / 4 + DIM / 4), 256, 0, stream>>>(x, nw, W, xn8, W8, rr);
    gemm_ep_kernel<<<dim3((NTOK / BM) * (DIM / BN)), dim3(512), 0, stream>>>(
        xn8, W8, x, rr, nw, sw, gamma, out);
}

// Round 21
// 37.997 us; speedup vs baseline: 2.1639x; 1.5325x over previous
//
#include <hip/hip_runtime.h>
#include <hip/hip_bf16.h>
#include <stdint.h>

#define DIM 1024
#define NTOK 8192

#define BM 128
#define BN 128
#define BK 64            // fp8: 64 bytes per row-tile

typedef unsigned char uchar;
typedef __attribute__((ext_vector_type(4)))  int   i32x4;
typedef __attribute__((ext_vector_type(8)))  int   i32x8;
typedef __attribute__((ext_vector_type(16))) float f32x16;

// async global->LDS, 16B per lane (dest = wave base + lane*16, linear)
#define GLOAD_LDS16(g, l)                                                \
    __builtin_amdgcn_global_load_lds(                                    \
        (const __attribute__((address_space(1))) void*)(g),              \
        (__attribute__((address_space(3))) void*)(l), 16, 0, 0)

__device__ __forceinline__ unsigned short f2bf(float f) {
    union { float f; uint32_t u; } v; v.f = f;
    uint32_t u = v.u;
    u += 0x7FFFu + ((u >> 16) & 1u);   // RNE
    return (unsigned short)(u >> 16);
}
__device__ __forceinline__ float bf2f(unsigned short h) {
    union { uint32_t u; float f; } v; v.u = ((uint32_t)h) << 16; return v.f;
}

// Closed-form uniform cubic B-spline (knots -2.2 + 0.55*i; weights s0..s4)
__device__ __forceinline__ float spline_eval(float xn, float s0, float s1,
                                             float s2, float s3, float s4) {
    const float xc = fminf(fmaxf(xn, -1.0f), 1.0f);
    const float u = (xc + 2.2f) * (1.0f / 0.55f);
    int j = (int)u;
    j = j < 2 ? 2 : (j > 5 ? 5 : j);
    const float t = u - (float)j;
    const float omt = 1.0f - t;
    const float t2 = t * t, t3 = t2 * t;
    const float w0 = omt * omt * omt * (1.0f / 6.0f);
    const float w1 = (3.0f * t3 - 6.0f * t2 + 4.0f) * (1.0f / 6.0f);
    const float w2 = (-3.0f * t3 + 3.0f * t2 + 3.0f * t + 1.0f) * (1.0f / 6.0f);
    const float w3 = t3 * (1.0f / 6.0f);
    float so;
    if (j == 2)      so = w1 * s0 + w2 * s1 + w3 * s2;
    else if (j == 3) so = w0 * s0 + w1 * s1 + w2 * s2 + w3 * s3;
    else if (j == 4) so = w0 * s1 + w1 * s2 + w2 * s3 + w3 * s4;
    else             so = w0 * s2 + w1 * s3 + w2 * s4;
    return so;
}

__device__ __forceinline__ int pack_fp8x4(float a, float b, float c, float d) {
    int p = __builtin_amdgcn_cvt_pk_fp8_f32(a, b, 0, false);   // bytes 0,1
    p = __builtin_amdgcn_cvt_pk_fp8_f32(c, d, p, true);        // bytes 2,3
    return p;
}

// ---------------------------------------------------------------------------
// Kernel 0 (wave-per-row, no LDS/no barriers):
//   blocks [0, NTOK/4): 4 waves x 1 row RMSNorm -> xn8 (fp8) + rr[row]
//   blocks [NTOK/4, NTOK/4 + DIM/4): 4 waves x 1 W row f32 -> fp8
// prep is at its HBM roofline (~45 MB -> ~7 us).
// ---------------------------------------------------------------------------
__global__ __launch_bounds__(256) void prep_kernel(
    const float* __restrict__ x, const float* __restrict__ nw,
    const float* __restrict__ W,
    uchar* __restrict__ xn8, uchar* __restrict__ W8,
    float* __restrict__ rr)
{
    const int bid = blockIdx.x;
    const int t = threadIdx.x;
    const int lane = t & 63, w = t >> 6;

    if (bid >= NTOK / 4) {                 // W conversion: 4 rows per block
        const int row = (bid - NTOK / 4) * 4 + w;
        const float4* src = reinterpret_cast<const float4*>(W + (size_t)row * DIM) + lane * 4;
        const float4 a = src[0], b = src[1], c = src[2], d = src[3];
        int4 o;
        o.x = pack_fp8x4(a.x, a.y, a.z, a.w);
        o.y = pack_fp8x4(b.x, b.y, b.z, b.w);
        o.z = pack_fp8x4(c.x, c.y, c.z, c.w);
        o.w = pack_fp8x4(d.x, d.y, d.z, d.w);
        reinterpret_cast<int4*>(W8 + (size_t)row * DIM)[lane] = o;
        return;
    }

    const int row = bid * 4 + w;
    const float4* xr = reinterpret_cast<const float4*>(x + (size_t)row * DIM) + lane * 4;
    const float4 a = xr[0], b = xr[1], c = xr[2], d = xr[3];

    float ssq = a.x*a.x + a.y*a.y + a.z*a.z + a.w*a.w
              + b.x*b.x + b.y*b.y + b.z*b.z + b.w*b.w
              + c.x*c.x + c.y*c.y + c.z*c.z + c.w*c.w
              + d.x*d.x + d.y*d.y + d.z*d.z + d.w*d.w;
    #pragma unroll
    for (int off = 32; off; off >>= 1) ssq += __shfl_xor(ssq, off, 64);

    const float r = rsqrtf(ssq * (1.0f / DIM) + 1e-6f);
    if (lane == 0) rr[row] = r;

    const float4* nwr = reinterpret_cast<const float4*>(nw) + lane * 4;
    const float4 na = nwr[0], nb = nwr[1], nc = nwr[2], nd = nwr[3];
    int4 o;
    o.x = pack_fp8x4(a.x*r*na.x, a.y*r*na.y, a.z*r*na.z, a.w*r*na.w);
    o.y = pack_fp8x4(b.x*r*nb.x, b.y*r*nb.y, b.z*r*nb.z, b.w*r*nb.w);
    o.z = pack_fp8x4(c.x*r*nc.x, c.y*r*nc.y, c.z*r*nc.z, c.w*r*nc.w);
    o.w = pack_fp8x4(d.x*r*nd.x, d.y*r*nd.y, d.z*r*nd.z, d.w*r*nd.w);
    reinterpret_cast<int4*>(xn8 + (size_t)row * DIM)[lane] = o;
}

// ---------------------------------------------------------------------------
// Kernel 1 (FINAL = r14, best measured 38.0us): MX-fp8 MFMA GEMM
//   C[n,d] = sum_k xn[n,k] * W[d,k], fused epilogue
//   out[n,d] = x[n,d] + (C[n,d] + spline(x*r*nw, sw[d,:])) * gamma[d]
// 16 waves (1024t) on a 128x128 tile (16 waves/CU -- VGPR=88 caps at 1
// block/CU; 2-block configs proven unreachable without spill, r18/r20).
// Per-wave 32x32 mfma_scale_32x32x64_f8f6f4 (scales=1.0). Waves 0-7 stage A,
// 8-15 stage B (1 load/thread/stage -> counted vmcnt W2/W1/W0). Ring-4 16KB
// bufs, raw s_barrier, verified swizzle pair (source unit (s&3)^((s>>3)&3),
// read XOR (lane>>1)&3), bf16-Cb single-pass epilogue.
// ---------------------------------------------------------------------------
__global__ __launch_bounds__(1024, 2) void gemm_ep_kernel(
    const uchar* __restrict__ A,   // xn fp8 [NTOK][DIM]
    const uchar* __restrict__ B,   // W  fp8 [DIM][DIM]
    const float* __restrict__ x,
    const float* __restrict__ rrow,         // [NTOK]
    const float* __restrict__ nw,           // [DIM]
    const float* __restrict__ sw,           // [DIM][5]
    const float* __restrict__ gamma,
    float* __restrict__ out)
{
    __shared__ uchar SB[4 * 16384];              // 64 KB: ring-4, A 8KB + B 8KB

    const int tid = threadIdx.x;
    const int lane = tid & 63, wid = tid >> 6;   // wid 0..15

    // XCD swizzle: 512 blocks, xcd = bid&7 gets 8 bm panels x all 8 bn
    const int bid = blockIdx.x;
    const int swz = (bid & 7) * 64 + (bid >> 3);
    const int bm = swz >> 3, bn = swz & 7;

    const int wm = wid >> 2, wn = wid & 3;       // 4x4 grid of 32x32 tiles

    f32x16 acc = {};

    // ---- staging: waves 0-7 stage A rows, waves 8-15 stage B rows.
    //      s = tid&511: row s>>2 (0..127), 16B unit s&3 (linear dest);
    //      global source unit pre-swizzled by ((s>>3)&3) = (row>>1)&3
    const int s = tid & 511;
    const int srow = s >> 2;
    const int scol = ((s & 3) ^ ((s >> 3) & 3)) * 16;     // bytes
    const uchar* Gsrc = (tid < 512)
        ? A + (size_t)(bm * BM + srow) * DIM + scol
        : B + (size_t)(bn * BN + srow) * DIM + scol;
    const int oS = (tid < 512 ? 0 : 8192) + s * 16;

    // ---- fragment read offsets (swizzled, verified r9..r17) ----
    const int xorv = (lane >> 1) & 3;
    const int u0 = ((lane >> 5) * 2) ^ xorv;  // 16B unit of k-bytes [kg*32,+16)
    const int u1 = u0 ^ 1;
    const int aBase = (wm * 32 + (lane & 31)) * 64;
    const int bBase = 8192 + (wn * 32 + (lane & 31)) * 64;

#define STAGE(bi, kt) do {                                           \
        GLOAD_LDS16(Gsrc + (size_t)(kt) * BK, SB + (bi) * 16384 + oS); \
    } while (0)

#define LD8(dst, base) do {                                          \
        const i32x4 lo_ = *reinterpret_cast<const i32x4*>(sb_ + (base) + u0 * 16); \
        const i32x4 hi_ = *reinterpret_cast<const i32x4*>(sb_ + (base) + u1 * 16); \
        dst = (i32x8){lo_[0], lo_[1], lo_[2], lo_[3],                \
                      hi_[0], hi_[1], hi_[2], hi_[3]};               \
    } while (0)

#define COMP(bi) do {                                                \
        const uchar* sb_ = SB + (bi) * 16384;                        \
        i32x8 a0, b0;                                                \
        LD8(a0, aBase);                                              \
        LD8(b0, bBase);                                              \
        acc = __builtin_amdgcn_mfma_scale_f32_32x32x64_f8f6f4(       \
            a0, b0, acc, 0, 0, 0, 0x7F7F7F7F, 0, 0x7F7F7F7F);        \
    } while (0)

#define W2v asm volatile("s_waitcnt vmcnt(2)" ::: "memory")
#define W1v asm volatile("s_waitcnt vmcnt(1)" ::: "memory")
#define W0v asm volatile("s_waitcnt vmcnt(0)" ::: "memory")
#define BAR __builtin_amdgcn_s_barrier()

    STAGE(0, 0);
    STAGE(1, 1);
    #pragma unroll 1
    for (int k4 = 0; k4 < 12; k4 += 4) {
        STAGE(2, k4 + 2); W2v; BAR; COMP(0);
        STAGE(3, k4 + 3); W2v; BAR; COMP(1);
        STAGE(0, k4 + 4); W2v; BAR; COMP(2);
        STAGE(1, k4 + 5); W2v; BAR; COMP(3);
    }
    STAGE(2, 14); W2v; BAR; COMP(0);   // kt=12
    STAGE(3, 15); W2v; BAR; COMP(1);   // kt=13
    W1v; BAR; COMP(2);                 // kt=14
    W0v; BAR; COMP(3);                 // kt=15
    __syncthreads();                   // all SB reads done before Cb overwrite

#undef STAGE
#undef LD8
#undef COMP
#undef W2v
#undef W1v
#undef W0v
#undef BAR

    // ---- fused epilogue: single-pass bf16 C-tile [128][136] (34 KB) ----
    unsigned short* Cb = reinterpret_cast<unsigned short*>(SB);
    {
        // C/D 32x32 layout: col=lane&31, row=(r&3)+8*(r>>2)+4*(lane>>5)
        const int crow0 = wm * 32 + 4 * (lane >> 5);
        const int ccol0 = wn * 32 + (lane & 31);
        #pragma unroll
        for (int r = 0; r < 16; ++r) {
            const int lr = crow0 + (r & 3) + 8 * (r >> 2);
            Cb[lr * 136 + ccol0] = f2bf(acc[r]);
        }
    }
    __syncthreads();

    const int colg = bn * BN + (tid & 31) * 4;   // 4 consecutive output cols
    float sf[20];
    {
        const float4* swp = reinterpret_cast<const float4*>(sw + (size_t)colg * 5);
        #pragma unroll
        for (int q = 0; q < 5; ++q) {
            const float4 w4 = swp[q];
            sf[q * 4 + 0] = w4.x; sf[q * 4 + 1] = w4.y;
            sf[q * 4 + 2] = w4.z; sf[q * 4 + 3] = w4.w;
        }
    }
    const float4 gv  = *reinterpret_cast<const float4*>(gamma + colg);
    const float4 nwv = *reinterpret_cast<const float4*>(nw + colg);

    #pragma unroll
    for (int v = 0; v < 4; ++v) {
        const int lr = (tid >> 5) * 4 + v;           // 0..127
        const size_t grow = (size_t)(bm * BM + lr);
        const ushort4 cb4 = *reinterpret_cast<const ushort4*>(&Cb[lr * 136 + (tid & 31) * 4]);
        const float4 xv = *reinterpret_cast<const float4*>(x + grow * DIM + colg);
        const float rv = rrow[grow];
        float4 ov;
        ov.x = xv.x + (bf2f(cb4.x) + spline_eval(xv.x * rv * nwv.x, sf[0],  sf[1],  sf[2],  sf[3],  sf[4]))  * gv.x;
        ov.y = xv.y + (bf2f(cb4.y) + spline_eval(xv.y * rv * nwv.y, sf[5],  sf[6],  sf[7],  sf[8],  sf[9]))  * gv.y;
        ov.z = xv.z + (bf2f(cb4.z) + spline_eval(xv.z * rv * nwv.z, sf[10], sf[11], sf[12], sf[13], sf[14])) * gv.z;
        ov.w = xv.w + (bf2f(cb4.w) + spline_eval(xv.w * rv * nwv.w, sf[15], sf[16], sf[17], sf[18], sf[19])) * gv.w;
        *reinterpret_cast<float4*>(out + grow * DIM + colg) = ov;
    }
}

// ---------------------------------------------------------------------------
extern "C" void kernel_launch(void* const* d_in, const int* in_sizes, int n_in,
                              void* d_out, int out_size, void* d_ws, size_t ws_size,
                              hipStream_t stream) {
    const float* x     = (const float*)d_in[0];
    const float* nw    = (const float*)d_in[1];
    const float* W     = (const float*)d_in[2];
    const float* sw    = (const float*)d_in[3];
    const float* gamma = (const float*)d_in[4];
    float* out = (float*)d_out;

    uchar* xn8 = (uchar*)d_ws;                                // 8 MB fp8 x_norm
    uchar* W8  = xn8 + (size_t)NTOK * DIM;                    // 1 MB fp8 W
    float* rr  = (float*)(W8 + (size_t)DIM * DIM);            // 32 KB row rsqrt

    prep_kernel<<<dim3(NTOK / 4 + DIM / 4), 256, 0, stream>>>(x, nw, W, xn8, W8, rr);
    gemm_ep_kernel<<<dim3((NTOK / BM) * (DIM / BN)), dim3(1024), 0, stream>>>(
        xn8, W8, x, rr, nw, sw, gamma, out);
}